// Round 4
// baseline (205.009 us; speedup 1.0000x reference)
//
#include <hip/hip_runtime.h>
#include <math.h>

#define N_ANCHORS 2048
#define BLOCK 256
#define THRESH 0.3f
#define OVERLAP 0.5f

__global__ __launch_bounds__(BLOCK) void det_kernel(
    const float* __restrict__ loc,    // (8, 2048, 2)
    const float* __restrict__ cls,    // (8, 2048, 5)
    const float* __restrict__ defs,   // (2048, 2)
    float* __restrict__ out)          // (8, 4, 2048, 3)
{
#pragma clang fp contract(off)
    const int tid  = threadIdx.x;
    const int lane = tid & 63;
    const int wid  = tid >> 6;
    const int bc   = blockIdx.x;   // 0..31
    const int b    = bc >> 2;
    const int c    = bc & 3;       // softmax component c+1

    // ~62 KB LDS
    __shared__ __align__(16) float  csc[N_ANCHORS + 4];    // score, compacted order (+pad)
    __shared__ __align__(16) float2 cbx[N_ANCHORS];        // box, compacted order
    __shared__ int                  cid[N_ANCHORS];        // anchor id, compacted
    __shared__ __align__(16) float2 sbox[N_ANCHORS + 64];  // box, sorted order (+chunk pad)
    __shared__ int                  sinv[N_ANCHORS];       // sorted pos -> compacted pos
    __shared__ unsigned char        sup[N_ANCHORS];        // suppressed (sorted pos)
    __shared__ unsigned char        kfl[N_ANCHORS];        // kept (sorted pos)
    __shared__ int s_wsum[4], s_woff[4], s_V;
    __shared__ unsigned long long s_km;

    // ---- Phase 0: zero output early (fire-and-forget; later barriers drain) ----
    float* const outb = out + (size_t)bc * N_ANCHORS * 3;
    {
        float4 z4 = make_float4(0.f, 0.f, 0.f, 0.f);
        float4* ob4 = (float4*)outb;
        for (int i = tid; i < (N_ANCHORS * 3) / 4; i += BLOCK) ob4[i] = z4;
    }
    for (int i = tid; i < N_ANCHORS; i += BLOCK) { sup[i] = 0; kfl[i] = 0; }

    // ---- Phase 1: vector loads + softmax + decode, 8 consecutive anchors/thread ----
    // (consecutive ownership => ordered compaction => compacted order ==
    //  original-index order == stable-argsort tie-break order)
    const int base = tid * 8;
    float c40[40], l16[16], d16[16];
    {
        const float4* cp4 = (const float4*)(cls + ((size_t)b * N_ANCHORS + base) * 5);
        const float4* lp4 = (const float4*)(loc + ((size_t)b * N_ANCHORS + base) * 2);
        const float4* dp4 = (const float4*)(defs + (size_t)base * 2);
#pragma unroll
        for (int q = 0; q < 10; ++q) ((float4*)c40)[q] = cp4[q];
#pragma unroll
        for (int q = 0; q < 4; ++q)  ((float4*)l16)[q] = lp4[q];
#pragma unroll
        for (int q = 0; q < 4; ++q)  ((float4*)d16)[q] = dp4[q];
    }
    float sc8[8], bs8[8], be8[8];
    int vmask = 0, cnt = 0;
#pragma unroll
    for (int k = 0; k < 8; ++k) {
        float x0 = c40[5*k+0], x1 = c40[5*k+1], x2 = c40[5*k+2],
              x3 = c40[5*k+3], x4 = c40[5*k+4];
        float m  = fmaxf(fmaxf(fmaxf(fmaxf(x0, x1), x2), x3), x4);
        float e0 = expf(x0 - m), e1 = expf(x1 - m), e2 = expf(x2 - m),
              e3 = expf(x3 - m), e4 = expf(x4 - m);
        float sum = e0 + e1 + e2 + e3 + e4;
        float ec  = (c == 0) ? e1 : (c == 1) ? e2 : (c == 2) ? e3 : e4;
        float score = ec / sum;

        float l0 = l16[2*k], l1 = l16[2*k+1];
        float d0 = d16[2*k], d1 = d16[2*k+1];
        float cc = d0 + l0 * d1;
        float w  = d1 * expf(l1);
        sc8[k] = score;
        bs8[k] = cc - 0.5f * w;
        be8[k] = cc + 0.5f * w;
        if (score > THRESH) { vmask |= (1 << k); cnt++; }
    }

    // ---- ordered compaction via block exclusive scan ----
    int inc = cnt;
    for (int d = 1; d < 64; d <<= 1) {
        int v = __shfl_up(inc, d);
        if (lane >= d) inc += v;
    }
    if (lane == 63) s_wsum[wid] = inc;
    __syncthreads();
    if (tid == 0) {
        int off = 0;
        for (int w = 0; w < 4; ++w) { s_woff[w] = off; off += s_wsum[w]; }
        s_V = off;
    }
    __syncthreads();
    int off = s_woff[wid] + (inc - cnt);
#pragma unroll
    for (int k = 0; k < 8; ++k) {
        if (vmask & (1 << k)) {
            csc[off] = sc8[k];
            cbx[off] = make_float2(bs8[k], be8[k]);
            cid[off] = base + k;
            off++;
        }
    }
    __syncthreads();
    const int V   = s_V;
    const int W   = (V + 63) >> 6;
    const int W64 = W << 6;

    // ---- Phase 1.5: pads (csc tail for float4 rank; sbox tail = inert box) ----
    if (tid < 4) csc[V + tid] = -INFINITY;
    for (int i = V + tid; i < W64; i += BLOCK) sbox[i] = make_float2(1e30f, 1e30f);
    __syncthreads();

    // ---- Phase 2: counting rank (score desc, compacted-pos asc) ----
    if (V <= 2 * BLOCK) {
        // fast path: <=2 positions/thread, one float4 stream pass
        int   p0 = tid,        p1 = tid + BLOCK;
        bool  a0 = p0 < V,     a1 = p1 < V;
        float m0 = a0 ? csc[p0] : INFINITY;
        float m1 = a1 ? csc[p1] : INFINITY;
        int   r0 = 0, r1 = 0;
        const float4* cs4 = (const float4*)csc;
        const int n4 = (V + 3) >> 2;
        for (int i4 = 0; i4 < n4; ++i4) {
            float4 s4 = cs4[i4];
            int ib = i4 << 2;
            r0 += (s4.x > m0 || (s4.x == m0 && ib + 0 < p0)) ? 1 : 0;
            r0 += (s4.y > m0 || (s4.y == m0 && ib + 1 < p0)) ? 1 : 0;
            r0 += (s4.z > m0 || (s4.z == m0 && ib + 2 < p0)) ? 1 : 0;
            r0 += (s4.w > m0 || (s4.w == m0 && ib + 3 < p0)) ? 1 : 0;
            r1 += (s4.x > m1 || (s4.x == m1 && ib + 0 < p1)) ? 1 : 0;
            r1 += (s4.y > m1 || (s4.y == m1 && ib + 1 < p1)) ? 1 : 0;
            r1 += (s4.z > m1 || (s4.z == m1 && ib + 2 < p1)) ? 1 : 0;
            r1 += (s4.w > m1 || (s4.w == m1 && ib + 3 < p1)) ? 1 : 0;
        }
        if (a0) { sinv[r0] = p0; sbox[r0] = cbx[p0]; }
        if (a1) { sinv[r1] = p1; sbox[r1] = cbx[p1]; }
    } else {
        // generic fallback (shouldn't trigger at this data distribution)
        for (int p = tid; p < V; p += BLOCK) {
            float s = csc[p];
            int r = 0;
            for (int i = 0; i < V; ++i) {
                float si = csc[i];
                r += ((si > s) || (si == s && i < p)) ? 1 : 0;
            }
            sinv[r] = p;
            sbox[r] = cbx[p];
        }
    }
    __syncthreads();

    // ---- Phase 3: chunked bitmask greedy NMS, fixed-trip loops ----
    for (int t = 0; t < W; ++t) {
        const int q0 = t << 6;
        if (wid == 0) {
            const int  q   = q0 + lane;
            const bool act = (q < V);
            float2 my = sbox[q];              // pads are inert
            float  mylen = my.y - my.x;
            bool   pre = act && !sup[q];

            unsigned long long supmask = 0ull;
            const float4* sb4 = (const float4*)(sbox + q0);
#pragma unroll
            for (int ii = 0; ii < 32; ++ii) {
                float4 bp = sb4[ii];
                float in0 = fmaxf(fminf(my.y, bp.y) - fmaxf(my.x, bp.x), 0.0f);
                float un0 = (bp.y - bp.x) + mylen - in0;
                float io0 = in0 / fmaxf(un0, 1e-12f);
                float in1 = fmaxf(fminf(my.y, bp.w) - fmaxf(my.x, bp.z), 0.0f);
                float un1 = (bp.w - bp.z) + mylen - in1;
                float io1 = in1 / fmaxf(un1, 1e-12f);
                int i0 = 2 * ii, i1 = 2 * ii + 1;
                if (io0 > OVERLAP && i0 < lane) supmask |= (1ull << i0);
                if (io1 > OVERLAP && i1 < lane) supmask |= (1ull << i1);
            }
            // greedy resolve (inherently serial chain)
            unsigned long long cand = __ballot(pre);
            unsigned long long kept = 0ull;
            while (cand) {
                int i = __builtin_ctzll(cand);
                kept |= (1ull << i);
                unsigned long long supn = __ballot(((supmask >> i) & 1ull) != 0ull);
                cand &= ~(supn | (1ull << i));
            }
            if (act) kfl[q] = (unsigned char)((kept >> lane) & 1ull);
            if (lane == 0) s_km = kept;
        }
        __syncthreads();

        // all waves: apply chunk t's kept set to later positions (fixed 64-trip)
        unsigned long long km = s_km;
        if (km) {
            const float4* sb4 = (const float4*)(sbox + q0);
            for (int qb = q0 + 64 + tid; qb < V; qb += BLOCK) {
                if (!sup[qb]) {
                    float2 mb = sbox[qb];
                    float  ml = mb.y - mb.x;
                    bool sflag = false;
#pragma unroll
                    for (int ii = 0; ii < 32; ++ii) {
                        float4 bp = sb4[ii];
                        float in0 = fmaxf(fminf(mb.y, bp.y) - fmaxf(mb.x, bp.x), 0.0f);
                        float un0 = (bp.y - bp.x) + ml - in0;
                        bool  s0  = (in0 / fmaxf(un0, 1e-12f)) > OVERLAP;
                        float in1 = fmaxf(fminf(mb.y, bp.w) - fmaxf(mb.x, bp.z), 0.0f);
                        float un1 = (bp.w - bp.z) + ml - in1;
                        bool  s1  = (in1 / fmaxf(un1, 1e-12f)) > OVERLAP;
                        unsigned long long bits = km >> (2 * ii);
                        sflag |= (s0 && (bits & 1ull));
                        sflag |= (s1 && (bits & 2ull));
                    }
                    if (sflag) sup[qb] = 1;
                }
            }
        }
        __syncthreads();
    }

    // ---- Phase 4: scatter kept boxes (in_range applied at output only) ----
    for (int r = tid; r < V; r += BLOCK) {
        if (kfl[r]) {
            float2 bx = sbox[r];
            if (bx.x > -10.0f && bx.y < 10.0f) {
                int p = sinv[r];
                int n = cid[p];
                float* o = outb + (size_t)n * 3;
                o[0] = bx.x;
                o[1] = bx.y;
                o[2] = csc[p];
            }
        }
    }
}

extern "C" void kernel_launch(void* const* d_in, const int* in_sizes, int n_in,
                              void* d_out, int out_size, void* d_ws, size_t ws_size,
                              hipStream_t stream) {
    const float* loc  = (const float*)d_in[0];  // localizations (8,2048,2)
    const float* cls  = (const float*)d_in[1];  // classifications (8,2048,5)
    const float* defs = (const float*)d_in[2];  // localizations_default (2048,2)
    float* out = (float*)d_out;                 // (8,4,2048,3) fp32
    det_kernel<<<32, BLOCK, 0, stream>>>(loc, cls, defs, out);
}

// Round 5
// 186.167 us; speedup vs baseline: 1.1012x; 1.1012x over previous
//
#include <hip/hip_runtime.h>
#include <math.h>

#define N_ANCHORS 2048
#define BLOCK 512
#define THRESH 0.3f
#define OVERLAP 0.5f

// Manual LDS pool: stage A (compacted, anchor order) then stage B (sorted
// order) alias the same bytes; handoff goes through registers + a barrier.
#define OFF_CSC   0        // float[2052]   stage A  (8208 B)
#define OFF_CBX   8208     // float2[2048]  stage A  (16384 B)
#define OFF_CID   24592    // ushort[2048]  stage A  (4096 B)
#define OFF_SBOX  0        // float2[2112]  stage B  (16896 B)
#define OFF_SSC   16896    // float[2048]   stage B  (8192 B)
#define OFF_SID   25088    // ushort[2048]  stage B  (4096 B)
#define POOL_SZ   29184

__global__ __launch_bounds__(BLOCK) void det_kernel(
    const float* __restrict__ loc,    // (8, 2048, 2)
    const float* __restrict__ cls,    // (8, 2048, 5)
    const float* __restrict__ defs,   // (2048, 2)
    float* __restrict__ out)          // (8, 4, 2048, 3)
{
#pragma clang fp contract(off)
    const int tid  = threadIdx.x;
    const int lane = tid & 63;
    const int wid  = tid >> 6;        // 0..7
    const int bc   = blockIdx.x;      // 0..31
    const int b    = bc >> 2;
    const int c    = bc & 3;          // softmax component c+1

    __shared__ __align__(16) unsigned char pool[POOL_SZ];
    __shared__ __align__(16) unsigned long long suprow[512 * 8];  // 32 KB
    __shared__ unsigned long long keptg[32];                      // kept bits, all sorted pos
    __shared__ unsigned long long candv[8], newkv[8], deadw[8], suppw[8];
    __shared__ int s_wsum[8], s_woff[8], s_V, s_done;

    float*          csc  = (float*)(pool + OFF_CSC);
    float2*         cbx  = (float2*)(pool + OFF_CBX);
    unsigned short* cid  = (unsigned short*)(pool + OFF_CID);
    float2*         sbox = (float2*)(pool + OFF_SBOX);
    float*          ssc  = (float*)(pool + OFF_SSC);
    unsigned short* sid  = (unsigned short*)(pool + OFF_SID);

    // ---- Phase 0: zero output (fire-and-forget; barriers drain vmcnt) ----
    float* const outb = out + (size_t)bc * N_ANCHORS * 3;
    {
        float4 z4 = make_float4(0.f, 0.f, 0.f, 0.f);
        float4* ob4 = (float4*)outb;
        for (int i = tid; i < (N_ANCHORS * 3) / 4; i += BLOCK) ob4[i] = z4;
    }
    if (tid < 32) keptg[tid] = 0ull;

    // ---- Phase 1: float4 loads + softmax + decode, 4 consecutive anchors ----
    const int base = tid * 4;
    float c20[20], l8v[8], d8v[8];
    {
        const float4* cp4 = (const float4*)(cls + ((size_t)b * N_ANCHORS + base) * 5);
#pragma unroll
        for (int q = 0; q < 5; ++q) ((float4*)c20)[q] = cp4[q];
        const float4* lp4 = (const float4*)(loc + ((size_t)b * N_ANCHORS + base) * 2);
        ((float4*)l8v)[0] = lp4[0]; ((float4*)l8v)[1] = lp4[1];
        const float4* dp4 = (const float4*)(defs + (size_t)base * 2);
        ((float4*)d8v)[0] = dp4[0]; ((float4*)d8v)[1] = dp4[1];
    }
    float sc4[4], bs4[4], be4[4];
    int vmask = 0, cnt = 0;
#pragma unroll
    for (int k = 0; k < 4; ++k) {
        float x0 = c20[5*k+0], x1 = c20[5*k+1], x2 = c20[5*k+2],
              x3 = c20[5*k+3], x4 = c20[5*k+4];
        float m  = fmaxf(fmaxf(fmaxf(fmaxf(x0, x1), x2), x3), x4);
        float e0 = expf(x0 - m), e1 = expf(x1 - m), e2 = expf(x2 - m),
              e3 = expf(x3 - m), e4 = expf(x4 - m);
        float sum = e0 + e1 + e2 + e3 + e4;
        float ec  = (c == 0) ? e1 : (c == 1) ? e2 : (c == 2) ? e3 : e4;
        float score = ec / sum;
        float l0 = l8v[2*k], l1 = l8v[2*k+1];
        float d0 = d8v[2*k], d1 = d8v[2*k+1];
        float cc = d0 + l0 * d1;
        float w  = d1 * expf(l1);
        sc4[k] = score;
        bs4[k] = cc - 0.5f * w;
        be4[k] = cc + 0.5f * w;
        if (score > THRESH) { vmask |= (1 << k); cnt++; }
    }

    // ---- ordered compaction (compacted order == anchor order) ----
    int inc = cnt;
    for (int d = 1; d < 64; d <<= 1) {
        int v = __shfl_up(inc, d);
        if (lane >= d) inc += v;
    }
    if (lane == 63) s_wsum[wid] = inc;
    __syncthreads();
    if (tid == 0) {
        int o = 0;
        for (int w = 0; w < 8; ++w) { s_woff[w] = o; o += s_wsum[w]; }
        s_V = o;
    }
    __syncthreads();
    {
        int off = s_woff[wid] + (inc - cnt);
#pragma unroll
        for (int k = 0; k < 4; ++k) {
            if (vmask & (1 << k)) {
                csc[off] = sc4[k];
                cbx[off] = make_float2(bs4[k], be4[k]);
                cid[off] = (unsigned short)(base + k);
                off++;
            }
        }
    }
    const int V = s_V;          // safe: read after barrier above? s_V set pre-barrier2
    __syncthreads();
    const int Wall = (V + 63) >> 6;
    if (tid < 4) csc[V + tid] = -INFINITY;   // pad for float4 rank stream
    __syncthreads();

    // ---- Phase 2: counting rank (score desc, anchor-order asc on ties) ----
    // Gather to REGISTERS before stage-B overwrites stage-A bytes.
    int   rr[4]; float2 rb[4]; float rs[4]; int rid[4]; int nown = 0;
    for (int p = tid; p < V; p += BLOCK) {
        float s = csc[p];
        int r = 0;
        const float4* cs4 = (const float4*)csc;
        const int n4 = (V + 3) >> 2;
        for (int i4 = 0; i4 < n4; ++i4) {
            float4 s4 = cs4[i4];
            int ib = i4 << 2;
            r += (s4.x > s || (s4.x == s && ib + 0 < p)) ? 1 : 0;
            r += (s4.y > s || (s4.y == s && ib + 1 < p)) ? 1 : 0;
            r += (s4.z > s || (s4.z == s && ib + 2 < p)) ? 1 : 0;
            r += (s4.w > s || (s4.w == s && ib + 3 < p)) ? 1 : 0;
        }
        rr[nown] = r; rb[nown] = cbx[p]; rs[nown] = s; rid[nown] = cid[p]; nown++;
    }
    __syncthreads();   // all stage-A reads done
    for (int q = 0; q < nown; ++q) {
        sbox[rr[q]] = rb[q];
        ssc[rr[q]]  = rs[q];
        sid[rr[q]]  = (unsigned short)rid[q];
    }
    for (int i = V + tid; i < (Wall << 6); i += BLOCK)
        sbox[i] = make_float2(1e30f, 1e30f);   // inert pad (IoU == 0)
    __syncthreads();

    // ---- Phase 3: super-chunks of 512 sorted boxes ----
    for (int s0 = 0; s0 < V; s0 += 512) {
        const int scn = (V - s0 < 512) ? (V - s0) : 512;
        const int scw = (scn + 63) >> 6;
        const int i   = tid;                 // box index within super-chunk
        const bool own = (i < scn);
        float2 my = own ? sbox[s0 + i] : make_float2(1e30f, 1e30f);
        float  ml = my.y - my.x;

        // (a) apply earlier super-chunks' kept boxes (fallback only; s0==0 skips)
        bool dead = false;
        const int ew_n = s0 >> 6;
        for (int ew = 0; ew < ew_n; ++ew) {
            unsigned long long kw = keptg[ew];   // wave-uniform
            if (kw) {
                const float4* sb4 = (const float4*)(sbox + (ew << 6));
#pragma unroll
                for (int jj = 0; jj < 32; ++jj) {
                    float4 bp = sb4[jj];
                    float in0 = fmaxf(fminf(my.y, bp.y) - fmaxf(my.x, bp.x), 0.0f);
                    float un0 = (bp.y - bp.x) + ml - in0;
                    float io0 = in0 / fmaxf(un0, 1e-12f);
                    float in1 = fmaxf(fminf(my.y, bp.w) - fmaxf(my.x, bp.z), 0.0f);
                    float un1 = (bp.w - bp.z) + ml - in1;
                    float io1 = in1 / fmaxf(un1, 1e-12f);
                    unsigned long long bits = kw >> (2 * jj);
                    dead |= (io0 > OVERLAP) && ((bits & 1ull) != 0ull);
                    dead |= (io1 > OVERLAP) && ((bits & 2ull) != 0ull);
                }
            }
        }
        dead = dead && own;
        {
            unsigned long long db = __ballot(dead);
            if (lane == 0) deadw[wid] = db;
        }

        // (b) build suppression bit-matrix rows in parallel.
        // Row u = bits j<u (within super-chunk) with IoU>0.5.
        // Wave w computes words 0..w: trip count wave-uniform, no divergence.
        {
            unsigned long long row[8];
#pragma unroll
            for (int w = 0; w < 8; ++w) row[w] = 0ull;
            if (own) {
                for (int w = 0; w <= wid; ++w) {
                    const float4* sb4 = (const float4*)(sbox + s0 + (w << 6));
                    unsigned long long word = 0ull;
#pragma unroll
                    for (int jj = 0; jj < 32; ++jj) {
                        float4 bp = sb4[jj];
                        float in0 = fmaxf(fminf(my.y, bp.y) - fmaxf(my.x, bp.x), 0.0f);
                        float un0 = (bp.y - bp.x) + ml - in0;
                        float io0 = in0 / fmaxf(un0, 1e-12f);
                        float in1 = fmaxf(fminf(my.y, bp.w) - fmaxf(my.x, bp.z), 0.0f);
                        float un1 = (bp.w - bp.z) + ml - in1;
                        float io1 = in1 / fmaxf(un1, 1e-12f);
                        int j0 = (w << 6) + 2 * jj;
                        if (io0 > OVERLAP && j0     < i) word |= (1ull << (2 * jj));
                        if (io1 > OVERLAP && j0 + 1 < i) word |= (1ull << (2 * jj + 1));
                    }
                    row[w] = word;
                }
            }
#pragma unroll
            for (int w = 0; w < 8; ++w) suprow[(i << 3) + w] = row[w];
        }
        __syncthreads();

        // (c) scalar init of candidate vector
        if (tid == 0) {
            for (int w = 0; w < 8; ++w) {
                int rem = scn - (w << 6);
                unsigned long long valid =
                    (rem >= 64) ? ~0ull : (rem > 0 ? ((1ull << rem) - 1ull) : 0ull);
                candv[w] = valid & ~deadw[w];
                newkv[w] = 0ull;
            }
            s_done = 0;
        }
        __syncthreads();

        // (d) exact greedy fixpoint: u kept iff no earlier kept suppresses u.
        // Per pass: dead = row∩newkept (remove), supp = row∩cand;
        // newkeep = cand & ~supp (safe: no possible suppressor remains);
        // if empty, lowest candidate is provably kept.
        for (int it = 0; it < 520; ++it) {
            bool dd = false, ss = false;
            if (own) {
                const unsigned long long* row = suprow + (i << 3);
                unsigned long long a = 0ull, bb = 0ull;
#pragma unroll
                for (int w = 0; w < 8; ++w) {
                    unsigned long long rw = row[w];
                    a  |= rw & newkv[w];
                    bb |= rw & candv[w];
                }
                dd = (a != 0ull); ss = (bb != 0ull);
            }
            unsigned long long dbal = __ballot(dd);
            unsigned long long sbal = __ballot(ss);
            if (lane == 0) { deadw[wid] = dbal; suppw[wid] = sbal; }
            __syncthreads();
            if (tid == 0) {
                unsigned long long nk[8];
                unsigned long long nko = 0ull;
                for (int w = 0; w < scw; ++w) candv[w] &= ~deadw[w];
                for (int w = 0; w < 8; ++w) nk[w] = 0ull;
                for (int w = 0; w < scw; ++w) { nk[w] = candv[w] & ~suppw[w]; nko |= nk[w]; }
                if (nko == 0ull) {
                    for (int w = 0; w < scw; ++w)
                        if (candv[w]) { nk[w] = candv[w] & (~candv[w] + 1ull); break; }
                }
                unsigned long long anyc = 0ull;
                for (int w = 0; w < scw; ++w) {
                    newkv[w] = nk[w];
                    keptg[(s0 >> 6) + w] |= nk[w];
                    candv[w] &= ~nk[w];
                    anyc |= candv[w];
                }
                s_done = (anyc == 0ull) ? 1 : 0;
            }
            __syncthreads();
            if (s_done) break;
        }
    }

    // ---- Phase 4: scatter kept (in_range applied at output only) ----
    for (int r = tid; r < V; r += BLOCK) {
        if ((keptg[r >> 6] >> (r & 63)) & 1ull) {
            float2 bx = sbox[r];
            if (bx.x > -10.0f && bx.y < 10.0f) {
                int n = sid[r];
                float* o = outb + (size_t)n * 3;
                o[0] = bx.x;
                o[1] = bx.y;
                o[2] = ssc[r];
            }
        }
    }
}

extern "C" void kernel_launch(void* const* d_in, const int* in_sizes, int n_in,
                              void* d_out, int out_size, void* d_ws, size_t ws_size,
                              hipStream_t stream) {
    const float* loc  = (const float*)d_in[0];  // localizations (8,2048,2)
    const float* cls  = (const float*)d_in[1];  // classifications (8,2048,5)
    const float* defs = (const float*)d_in[2];  // localizations_default (2048,2)
    float* out = (float*)d_out;                 // (8,4,2048,3) fp32
    det_kernel<<<32, BLOCK, 0, stream>>>(loc, cls, defs, out);
}

// Round 6
// 169.129 us; speedup vs baseline: 1.2121x; 1.1007x over previous
//
#include <hip/hip_runtime.h>
#include <math.h>

#define N_ANCHORS 2048
#define BLOCK 512
#define THRESH 0.3f
#define OVERLAP 0.5f

// Manual LDS pool: stage A (compacted, anchor order) then stage B (sorted
// order) alias the same bytes; handoff goes through registers + a barrier.
#define OFF_CSC   0        // float[2052]   stage A  (8208 B)
#define OFF_CBX   8208     // float2[2048]  stage A  (16384 B)
#define OFF_CID   24592    // ushort[2048]  stage A  (4096 B)
#define OFF_SBOX  0        // float2[2112]  stage B  (16896 B)
#define OFF_SSC   16896    // float[2048]   stage B  (8192 B)
#define OFF_SID   25088    // ushort[2048]  stage B  (4096 B)
#define POOL_SZ   29184

#define TRI(k, w) ((k) * ((k) + 1) / 2 + (w))   // triangular row storage

__global__ __launch_bounds__(BLOCK) void det_kernel(
    const float* __restrict__ loc,    // (8, 2048, 2)
    const float* __restrict__ cls,    // (8, 2048, 5)
    const float* __restrict__ defs,   // (2048, 2)
    float* __restrict__ out)          // (8, 4, 2048, 3)
{
#pragma clang fp contract(off)
    const int tid  = threadIdx.x;
    const int lane = tid & 63;
    const int wid  = tid >> 6;        // 0..7
    const int bc   = blockIdx.x;      // 0..31
    const int b    = bc >> 2;
    const int c    = bc & 3;          // softmax component c+1

    __shared__ __align__(16) unsigned char pool[POOL_SZ];
    // transposed: suprowT[w*512 + u] = word w of box u's suppression row
    __shared__ __align__(16) unsigned long long suprowT[8 * 512];   // 32 KB
    __shared__ unsigned long long keptg[32];    // kept bits, global sorted pos
    __shared__ unsigned long long s_deadw[8];   // cross-superchunk dead words
    __shared__ int s_wsum[8], s_woff[8], s_V;

    float*          csc  = (float*)(pool + OFF_CSC);
    float2*         cbx  = (float2*)(pool + OFF_CBX);
    unsigned short* cid  = (unsigned short*)(pool + OFF_CID);
    float2*         sbox = (float2*)(pool + OFF_SBOX);
    float*          ssc  = (float*)(pool + OFF_SSC);
    unsigned short* sid  = (unsigned short*)(pool + OFF_SID);

    // ---- Phase 0: zero output (fire-and-forget; barriers drain vmcnt) ----
    float* const outb = out + (size_t)bc * N_ANCHORS * 3;
    {
        float4 z4 = make_float4(0.f, 0.f, 0.f, 0.f);
        float4* ob4 = (float4*)outb;
        for (int i = tid; i < (N_ANCHORS * 3) / 4; i += BLOCK) ob4[i] = z4;
    }
    if (tid < 32) keptg[tid] = 0ull;

    // ---- Phase 1: float4 loads + softmax + decode, 4 consecutive anchors ----
    const int base = tid * 4;
    float c20[20], l8v[8], d8v[8];
    {
        const float4* cp4 = (const float4*)(cls + ((size_t)b * N_ANCHORS + base) * 5);
#pragma unroll
        for (int q = 0; q < 5; ++q) ((float4*)c20)[q] = cp4[q];
        const float4* lp4 = (const float4*)(loc + ((size_t)b * N_ANCHORS + base) * 2);
        ((float4*)l8v)[0] = lp4[0]; ((float4*)l8v)[1] = lp4[1];
        const float4* dp4 = (const float4*)(defs + (size_t)base * 2);
        ((float4*)d8v)[0] = dp4[0]; ((float4*)d8v)[1] = dp4[1];
    }
    float sc4[4], bs4[4], be4[4];
    int vmask = 0, cnt = 0;
#pragma unroll
    for (int k = 0; k < 4; ++k) {
        float x0 = c20[5*k+0], x1 = c20[5*k+1], x2 = c20[5*k+2],
              x3 = c20[5*k+3], x4 = c20[5*k+4];
        float m  = fmaxf(fmaxf(fmaxf(fmaxf(x0, x1), x2), x3), x4);
        float e0 = expf(x0 - m), e1 = expf(x1 - m), e2 = expf(x2 - m),
              e3 = expf(x3 - m), e4 = expf(x4 - m);
        float sum = e0 + e1 + e2 + e3 + e4;
        float ec  = (c == 0) ? e1 : (c == 1) ? e2 : (c == 2) ? e3 : e4;
        float score = ec / sum;
        float l0 = l8v[2*k], l1 = l8v[2*k+1];
        float d0 = d8v[2*k], d1 = d8v[2*k+1];
        float cc = d0 + l0 * d1;
        float w  = d1 * expf(l1);
        sc4[k] = score;
        bs4[k] = cc - 0.5f * w;
        be4[k] = cc + 0.5f * w;
        if (score > THRESH) { vmask |= (1 << k); cnt++; }
    }

    // ---- ordered compaction (compacted order == anchor order) ----
    int inc = cnt;
    for (int d = 1; d < 64; d <<= 1) {
        int v = __shfl_up(inc, d);
        if (lane >= d) inc += v;
    }
    if (lane == 63) s_wsum[wid] = inc;
    __syncthreads();
    if (tid == 0) {
        int o = 0;
        for (int w = 0; w < 8; ++w) { s_woff[w] = o; o += s_wsum[w]; }
        s_V = o;
    }
    __syncthreads();
    {
        int off = s_woff[wid] + (inc - cnt);
#pragma unroll
        for (int k = 0; k < 4; ++k) {
            if (vmask & (1 << k)) {
                csc[off] = sc4[k];
                cbx[off] = make_float2(bs4[k], be4[k]);
                cid[off] = (unsigned short)(base + k);
                off++;
            }
        }
    }
    __syncthreads();
    const int V = s_V;
    const int Wall = (V + 63) >> 6;
    if (tid < 4) csc[V + tid] = -INFINITY;   // pad for float4 rank stream
    __syncthreads();

    // ---- Phase 2: counting rank (score desc, anchor-order asc on ties) ----
    // Gather to REGISTERS before stage-B overwrites stage-A bytes.
    int rr[4]; float2 rb[4]; float rs[4]; int ridv[4]; int nown = 0;
    if (V <= 512) {
        // fast path: 4 waves, 2 boxes/thread, one float4 stream pass
        if (tid < 256) {
            int   p0 = tid, p1 = tid + 256;
            bool  a0 = p0 < V, a1 = p1 < V;
            float m0 = a0 ? csc[p0] : INFINITY;
            float m1 = a1 ? csc[p1] : INFINITY;
            int   r0 = 0, r1 = 0;
            const float4* cs4 = (const float4*)csc;
            const int n4 = (V + 3) >> 2;
            for (int i4 = 0; i4 < n4; ++i4) {
                float4 s4 = cs4[i4];
                int ib = i4 << 2;
                r0 += (s4.x > m0 || (s4.x == m0 && ib + 0 < p0)) ? 1 : 0;
                r0 += (s4.y > m0 || (s4.y == m0 && ib + 1 < p0)) ? 1 : 0;
                r0 += (s4.z > m0 || (s4.z == m0 && ib + 2 < p0)) ? 1 : 0;
                r0 += (s4.w > m0 || (s4.w == m0 && ib + 3 < p0)) ? 1 : 0;
                r1 += (s4.x > m1 || (s4.x == m1 && ib + 0 < p1)) ? 1 : 0;
                r1 += (s4.y > m1 || (s4.y == m1 && ib + 1 < p1)) ? 1 : 0;
                r1 += (s4.z > m1 || (s4.z == m1 && ib + 2 < p1)) ? 1 : 0;
                r1 += (s4.w > m1 || (s4.w == m1 && ib + 3 < p1)) ? 1 : 0;
            }
            if (a0) { rr[nown] = r0; rb[nown] = cbx[p0]; rs[nown] = m0; ridv[nown] = cid[p0]; nown++; }
            if (a1) { rr[nown] = r1; rb[nown] = cbx[p1]; rs[nown] = m1; ridv[nown] = cid[p1]; nown++; }
        }
    } else {
        for (int p = tid; p < V; p += BLOCK) {
            float s = csc[p];
            int r = 0;
            const float4* cs4 = (const float4*)csc;
            const int n4 = (V + 3) >> 2;
            for (int i4 = 0; i4 < n4; ++i4) {
                float4 s4 = cs4[i4];
                int ib = i4 << 2;
                r += (s4.x > s || (s4.x == s && ib + 0 < p)) ? 1 : 0;
                r += (s4.y > s || (s4.y == s && ib + 1 < p)) ? 1 : 0;
                r += (s4.z > s || (s4.z == s && ib + 2 < p)) ? 1 : 0;
                r += (s4.w > s || (s4.w == s && ib + 3 < p)) ? 1 : 0;
            }
            rr[nown] = r; rb[nown] = cbx[p]; rs[nown] = s; ridv[nown] = cid[p]; nown++;
        }
    }
    __syncthreads();   // all stage-A reads done
    for (int q = 0; q < nown; ++q) {
        sbox[rr[q]] = rb[q];
        ssc[rr[q]]  = rs[q];
        sid[rr[q]]  = (unsigned short)ridv[q];
    }
    for (int i = V + tid; i < (Wall << 6); i += BLOCK)
        sbox[i] = make_float2(1e30f, 1e30f);   // inert pad (IoU == 0)
    __syncthreads();

    // ---- Phase 3: super-chunks of 512 sorted boxes (one pass when V<=512) ----
    for (int s0 = 0; s0 < V; s0 += 512) {
        const int scn = (V - s0 < 512) ? (V - s0) : 512;
        const int i   = tid;                 // box index within super-chunk
        const bool own = (i < scn);
        float2 my = own ? sbox[s0 + i] : make_float2(1e30f, 1e30f);
        float  ml = my.y - my.x;

        // (a) dead from earlier super-chunks' kept (no-op when s0 == 0)
        bool dead = false;
        const int ew_n = s0 >> 6;
        for (int ew = 0; ew < ew_n; ++ew) {
            unsigned long long kw = keptg[ew];   // wave-uniform
            if (kw) {
                const float4* sb4 = (const float4*)(sbox + (ew << 6));
#pragma unroll
                for (int jj = 0; jj < 32; ++jj) {
                    float4 bp = sb4[jj];
                    float in0 = fmaxf(fminf(my.y, bp.y) - fmaxf(my.x, bp.x), 0.0f);
                    float un0 = (bp.y - bp.x) + ml - in0;
                    float io0 = in0 / fmaxf(un0, 1e-12f);
                    float in1 = fmaxf(fminf(my.y, bp.w) - fmaxf(my.x, bp.z), 0.0f);
                    float un1 = (bp.w - bp.z) + ml - in1;
                    float io1 = in1 / fmaxf(un1, 1e-12f);
                    unsigned long long bits = kw >> (2 * jj);
                    dead |= (io0 > OVERLAP) && ((bits & 1ull) != 0ull);
                    dead |= (io1 > OVERLAP) && ((bits & 2ull) != 0ull);
                }
            }
        }
        {
            unsigned long long db = __ballot(dead && own);
            if (lane == 0) s_deadw[wid] = db;
        }

        // (b) build suppression rows, TRANSPOSED store (lane-consecutive b64).
        // Row u, word w (w <= stripe(u)): bit j set iff box (w*64+j) with
        // j-global < u has IoU > 0.5 with u.
        for (int w = 0; w <= wid; ++w) {
            unsigned long long word = 0ull;
            if (own) {
                const float4* sb4 = (const float4*)(sbox + s0 + (w << 6));
#pragma unroll
                for (int jj = 0; jj < 32; ++jj) {
                    float4 bp = sb4[jj];
                    float in0 = fmaxf(fminf(my.y, bp.y) - fmaxf(my.x, bp.x), 0.0f);
                    float un0 = (bp.y - bp.x) + ml - in0;
                    float io0 = in0 / fmaxf(un0, 1e-12f);
                    float in1 = fmaxf(fminf(my.y, bp.w) - fmaxf(my.x, bp.z), 0.0f);
                    float un1 = (bp.w - bp.z) + ml - in1;
                    float io1 = in1 / fmaxf(un1, 1e-12f);
                    int j0 = (w << 6) + 2 * jj;
                    if (io0 > OVERLAP && j0     < i) word |= (1ull << (2 * jj));
                    if (io1 > OVERLAP && j0 + 1 < i) word |= (1ull << (2 * jj + 1));
                }
            }
            suprowT[(w << 9) + i] = word;
        }
        __syncthreads();

        // (c) wave 0: register-resident greedy fixpoint. No LDS, no barriers
        // in the loop; 2 ballots per DAG level.
        if (wid == 0) {
            unsigned long long row[36];
#pragma unroll
            for (int k = 0; k < 8; ++k)
#pragma unroll
                for (int w = 0; w <= k; ++w)
                    row[TRI(k, w)] = suprowT[(w << 9) + (k << 6) + lane];
            unsigned long long sdead[8];
#pragma unroll
            for (int w = 0; w < 8; ++w) sdead[w] = s_deadw[w];

            unsigned long long kv[8];
#pragma unroll
            for (int w = 0; w < 8; ++w) {
                kv[w] = 0ull;
                if ((w << 6) < scn) {
                    bool dl = ((sdead[w] >> lane) & 1ull) != 0ull;
#pragma unroll
                    for (int w2 = 0; w2 < w; ++w2)
                        dl |= (row[TRI(w, w2)] & kv[w2]) != 0ull;
                    const unsigned long long rself = row[TRI(w, w)];
                    int rem = scn - (w << 6);
                    unsigned long long valid =
                        (rem >= 64) ? ~0ull : ((1ull << rem) - 1ull);
                    unsigned long long cand = valid & ~__ballot(dl);
                    unsigned long long kw = 0ull;
                    while (cand) {
                        unsigned long long suppw = __ballot((rself & cand) != 0ull);
                        unsigned long long nk = cand & ~suppw;
                        if (!nk) nk = cand & (~cand + 1ull);  // acyclic: unreachable
                        kw |= nk;
                        unsigned long long ddw = __ballot((rself & nk) != 0ull);
                        cand &= ~(nk | ddw);
                    }
                    kv[w] = kw;
                }
            }
            if (lane == 0) {
#pragma unroll
                for (int w = 0; w < 8; ++w) keptg[(s0 >> 6) + w] |= kv[w];
            }
        }
        __syncthreads();
    }

    // ---- Phase 4: scatter kept (in_range applied at output only) ----
    for (int r = tid; r < V; r += BLOCK) {
        if ((keptg[r >> 6] >> (r & 63)) & 1ull) {
            float2 bx = sbox[r];
            if (bx.x > -10.0f && bx.y < 10.0f) {
                int n = sid[r];
                float* o = outb + (size_t)n * 3;
                o[0] = bx.x;
                o[1] = bx.y;
                o[2] = ssc[r];
            }
        }
    }
}

extern "C" void kernel_launch(void* const* d_in, const int* in_sizes, int n_in,
                              void* d_out, int out_size, void* d_ws, size_t ws_size,
                              hipStream_t stream) {
    const float* loc  = (const float*)d_in[0];  // localizations (8,2048,2)
    const float* cls  = (const float*)d_in[1];  // classifications (8,2048,5)
    const float* defs = (const float*)d_in[2];  // localizations_default (2048,2)
    float* out = (float*)d_out;                 // (8,4,2048,3) fp32
    det_kernel<<<32, BLOCK, 0, stream>>>(loc, cls, defs, out);
}